// Round 11
// baseline (2385.407 us; speedup 1.0000x reference)
//
#include <hip/hip_runtime.h>
#include <stdint.h>

typedef unsigned short u16;
typedef unsigned int   u32;

typedef short bf16x8 __attribute__((ext_vector_type(8)));   // 8 bf16 in 4 VGPRs
typedef int   i32x4  __attribute__((ext_vector_type(4)));
typedef float f32x4  __attribute__((ext_vector_type(4)));

#define NROWS  2048
#define HID    256
#define BATCH  8
#define NSTEPS 10
#define MTILE  16            // rows per workgroup
#define NWGS   (NROWS/MTILE) // 128
#define THREADS 512          // 8 waves, 2/SIMD (LDS-capped)

// ---------- helpers ----------
__device__ __forceinline__ u16 f2bf(float f) {
    union { float f; u32 u; } v; v.f = f;
    u32 r = (v.u + 0x7FFFu + ((v.u >> 16) & 1u)) >> 16;   // RNE
    return (u16)r;
}
__device__ __forceinline__ float sigm(float x) {
    return 1.0f / (1.0f + __expf(-x));
}
__device__ __forceinline__ float ftanh(float x) {
    x = fminf(fmaxf(x, -15.0f), 15.0f);
    float a = __expf(2.0f * x);
    return (a - 1.0f) / (a + 1.0f);
}
__device__ __forceinline__ f32x4 mfma16(bf16x8 a, bf16x8 b, f32x4 c) {
    return __builtin_amdgcn_mfma_f32_16x16x32_bf16(a, b, c, 0, 0, 0);
}
__device__ __forceinline__ bf16x8 as_bf(i32x4 v) {
    union { i32x4 i; bf16x8 b; } u; u.i = v; return u.b;
}
// packed weight B-fragment load (plain path, residency fill only)
__device__ __forceinline__ bf16x8 loadB(const u16* __restrict__ base, int ct, int kt, int ln) {
    return ((const bf16x8*)base)[(ct * 8 + kt) * 64 + ln];
}
// barrier that does NOT drain vmcnt (stream loads stay in flight)
__device__ __forceinline__ void barrier_lgkm() {
    asm volatile("s_waitcnt lgkmcnt(0)" ::: "memory");
    __builtin_amdgcn_s_barrier();
    asm volatile("" ::: "memory");
}

// asm-pinned 4-frag (4KB) weight-group load: scheduler cannot sink these.
#define ISS(q0, q1, q2, q3, P) do {                                              \
    uint64_t _a = (uint64_t)(const void*)(P);                                    \
    asm volatile("global_load_dwordx4 %0, %1, off"             : "=v"(q0) : "v"(_a)); \
    asm volatile("global_load_dwordx4 %0, %1, off offset:1024" : "=v"(q1) : "v"(_a)); \
    asm volatile("global_load_dwordx4 %0, %1, off offset:2048" : "=v"(q2) : "v"(_a)); \
    asm volatile("global_load_dwordx4 %0, %1, off offset:3072" : "=v"(q3) : "v"(_a)); \
} while (0)

// consume a group: counted wait -- 3 younger groups (12 loads) stay in flight.
// sched_barrier(0) is the FULL fence (rule #18): register-only VALU copies of
// the q-regs must NOT be hoisted above the waitcnt (R10's 0x386 mask bug).
#define CONS(acc, AF, q0, q1, q2, q3) do {                                       \
    asm volatile("s_waitcnt vmcnt(12)" ::: "memory");                            \
    __builtin_amdgcn_sched_barrier(0);                                           \
    (acc) = mfma16(AF[0], as_bf(q0), (acc));                                     \
    (acc) = mfma16(AF[1], as_bf(q1), (acc));                                     \
    (acc) = mfma16(AF[2], as_bf(q2), (acc));                                     \
    (acc) = mfma16(AF[3], as_bf(q3), (acc));                                     \
} while (0)

// ---------- setup kernels (unchanged, validated) ----------
__global__ __launch_bounds__(256) void stode_wz(const float* __restrict__ Wf,
                                                const float* __restrict__ Ws2,
                                                float* __restrict__ Wz) {
    int a = blockIdx.x;
    int b = threadIdx.x;
    const float* wf2 = Wf + a * 512 + 256;
    float acc = 0.0f;
    for (int c = 0; c < 256; ++c) acc += wf2[c] * Ws2[c * 256 + b];
    Wz[a * 256 + b] = acc;
}
__global__ __launch_bounds__(256) void stode_biasf(const float* __restrict__ Wf,
                                                   const float* __restrict__ Ws2b,
                                                   const float* __restrict__ Wfb,
                                                   float* __restrict__ biasf) {
    int a = threadIdx.x;
    const float* wf2 = Wf + a * 512 + 256;
    float acc = Wfb[a];
    for (int c = 0; c < 256; ++c) acc += wf2[c] * Ws2b[c];
    biasf[a] = acc;
}
__global__ __launch_bounds__(256) void stode_pack(const float* __restrict__ Wg,
                                                  const float* __restrict__ Ws1,
                                                  const float* __restrict__ Wc,
                                                  const float* __restrict__ Wz,
                                                  const float* __restrict__ Wf,
                                                  u16* __restrict__ P1,
                                                  u16* __restrict__ P2,
                                                  u16* __restrict__ P3) {
    int i = blockIdx.x * 256 + threadIdx.x;
    const int NP1 = 48 * 8 * 64 * 8;
    const int NP2 = 32 * 8 * 64 * 8;
    int region, local;
    if (i < NP1)            { region = 0; local = i; }
    else if (i < NP1 + NP2) { region = 1; local = i - NP1; }
    else                    { region = 2; local = i - NP1 - NP2; }
    int j    = local & 7;
    int lane = (local >> 3) & 63;
    int kt   = (local >> 9) & 7;
    int ct   = local >> 12;
    int k = kt * 32 + (lane >> 4) * 8 + j;
    int c = lane & 15;
    if (region == 0) {
        float v = (ct < 32) ? Wg[(16 * ct + c) * 256 + k]
                            : Ws1[(16 * (ct - 32) + c) * 256 + k];
        P1[local] = f2bf(v);
    } else if (region == 1) {
        float v = (ct < 16) ? Wc[(16 * ct + c) * 256 + k]
                            : Wz[(16 * (ct - 16) + c) * 256 + k];
        P2[local] = f2bf(v);
    } else {
        float v = Wf[(16 * ct + c) * 512 + k];
        P3[local] = f2bf(v);
    }
}

// ---------- main persistent integrator ----------
// LDS: 3 rotating 8KB activation slots @0/8192/16384; R-resident @24576 (128KB). 152KB.
#define SLOT0 0
#define SLOT1 8192
#define SLOT2 16384
#define WLB   24576

__global__ __launch_bounds__(THREADS, 1) void stode_main(
    const float* __restrict__ h0, const float* __restrict__ tspans,
    const float* __restrict__ Wg_b, const float* __restrict__ Wc_b,
    const float* __restrict__ Wt,   const float* __restrict__ Ws1_b,
    const u16* __restrict__ P1p, const u16* __restrict__ P2p, const u16* __restrict__ P3p,
    const float* __restrict__ biasf, float* __restrict__ out)
{
    __shared__ __align__(1024) u16 SH[77824];   // 155648 bytes
    char* shb = (char*)SH;

    const int tid = threadIdx.x;
    const int wv  = tid >> 6;    // 0..7 : wave owns cts {2wv, 2wv+1} (cols 32wv..32wv+31)
    const int ln  = tid & 63;
    const int lr  = ln & 15;
    const int lg  = ln >> 4;
    const int wg  = blockIdx.x;
    const float third = 1.0f / 3.0f;

    // A-frag read bases: addr(k) = (k even ? tbE : tbO) + xb + k*64 (XOR swizzle)
    const int base0 = lr * 512 + ((lg * 16) ^ ((lr & 3) << 4));
    const int flp   = (lr & 4) ? 64 : 0;
    const int tbE   = base0 + flp;
    const int tbO   = base0 - flp;
    const int rBase = WLB + (wv << 14) + (ln << 4);   // R-resident: 16KB/wave

    auto ldAF = [&](bf16x8 (&af)[4], int xb, int ktH) {
        #pragma unroll
        for (int kk = 0; kk < 4; ++kk) {
            int k = 4 * ktH + kk;
            af[kk] = *(const bf16x8*)(shb + ((k & 1) ? tbO : tbE) + xb + k * 64);
        }
    };
    auto st16 = [&](int xb, int row, int col, u16 v) {
        int byte = (xb + row * 512 + col * 2) ^ ((row & 7) << 4);
        *(u16*)(shb + byte) = v;
    };
    auto ldsRf = [&](int t, int kt) -> bf16x8 {
        return *(const bf16x8*)(shb + rBase + ((t * 8 + kt) << 10));
    };

    // ---- one-time residency: R weights -> LDS (16 frags/wave) ----
    #pragma unroll
    for (int t = 0; t < 2; ++t)
        #pragma unroll
        for (int kt = 0; kt < 8; ++kt) {
            bf16x8 f = loadB(P1p, 16 + 2 * wv + t, kt, ln);
            *(bf16x8*)(shb + rBase + ((t * 8 + kt) << 10)) = f;
        }

    // stream base pointers (u16 units; frag = 512 u16, ct-block = 4096 u16, half = 2048)
    const u16* const baseZ = P1p + (2 * wv) * 4096 + ln * 8;
    const u16* const baseS = P1p + (32 + 2 * wv) * 4096 + ln * 8;
    const u16* const baseC = P2p + (2 * wv) * 4096 + ln * 8;
    const u16* const baseT = P2p + (16 + 2 * wv) * 4096 + ln * 8;
    const u16* const baseF = P3p + (2 * wv) * 4096 + ln * 8;

    // biases / Wt : cols = 32wv+lr, 32wv+16+lr
    float bz[2], br[2], bs1[2], bc[2], bfv[2], wtv[2];
    #pragma unroll
    for (int t = 0; t < 2; ++t) {
        int c = 32 * wv + 16 * t + lr;
        bz[t]  = Wg_b[c];
        br[t]  = Wg_b[256 + c];
        bs1[t] = Ws1_b[c];
        bc[t]  = Wc_b[c];
        bfv[t] = biasf[c];
        wtv[t] = Wt[c];
    }

    // state at C/D positions: row = 4*lg + r, col = 32wv + 16t + lr
    float y[2][4], kA[2][4], kB[2][4], zreg[2][4];
    #pragma unroll
    for (int t = 0; t < 2; ++t)
        #pragma unroll
        for (int r = 0; r < 4; ++r)
            y[t][r] = h0[(wg * MTILE + 4 * lg + r) * 256 + (32 * wv + 16 * t + lr)];

    __syncthreads();   // residency visible (full drain, once)

    // stream buffers (asm-pinned, 4 x 16 regs) -- groups rotate a,b,c,d
    i32x4 qa0, qa1, qa2, qa3, qb0, qb1, qb2, qb3;
    i32x4 qc0, qc1, qc2, qc3, qd0, qd1, qd2, qd3;
    // prologue: g0=Z(t0,h0), g1=Z(t1,h0), g2=S(t0,h0), g3=S(t1,h0)
    ISS(qa0, qa1, qa2, qa3, baseZ);
    ISS(qb0, qb1, qb2, qb3, baseZ + 4096);
    ISS(qc0, qc1, qc2, qc3, baseS);
    ISS(qd0, qd1, qd2, qd3, baseS + 4096);

    float dt = 0.0f;

    auto calcE = [&](float (&Ev)[2][4], int RK) {
        if (RK == 1) {
            #pragma unroll
            for (int t = 0; t < 2; ++t)
                #pragma unroll
                for (int r = 0; r < 4; ++r) Ev[t][r] = y[t][r];
        } else if (RK == 2) {
            float c = dt * third;
            #pragma unroll
            for (int t = 0; t < 2; ++t)
                #pragma unroll
                for (int r = 0; r < 4; ++r) Ev[t][r] = y[t][r] + c * kA[t][r];
        } else if (RK == 3) {
            #pragma unroll
            for (int t = 0; t < 2; ++t)
                #pragma unroll
                for (int r = 0; r < 4; ++r) Ev[t][r] = y[t][r] + dt * (kB[t][r] - third * kA[t][r]);
        } else {
            #pragma unroll
            for (int t = 0; t < 2; ++t)
                #pragma unroll
                for (int r = 0; r < 4; ++r) Ev[t][r] = y[t][r] + dt * kB[t][r];
        }
    };

    // rotating activation slots
    int bE = SLOT0, bRE = SLOT1, bTS = SLOT2;

    auto EVAL = [&](float te, int RK) {
        // E computed ONCE per eval (bit-identical expressions), reused 3x
        float Ev[2][4]; calcE(Ev, RK);

        // stage X_E = bf16(E)
        #pragma unroll
        for (int t = 0; t < 2; ++t)
            #pragma unroll
            for (int r = 0; r < 4; ++r)
                st16(bE, 4 * lg + r, 32 * wv + 16 * t + lr, f2bf(Ev[t][r]));
        barrier_lgkm();   // B1 (stream loads stay in flight)

        // ---- P1: Z (stream), R (LDS-resident), S (stream) ----
        f32x4 aZ[2], aR[2], aS[2];
        #pragma unroll
        for (int t = 0; t < 2; ++t) {
            aZ[t] = f32x4{0.f, 0.f, 0.f, 0.f};
            aR[t] = f32x4{0.f, 0.f, 0.f, 0.f};
            aS[t] = f32x4{0.f, 0.f, 0.f, 0.f};
        }
        bf16x8 af[4];
        ldAF(af, bE, 0);                                             // h0
        CONS(aZ[0], af, qa0, qa1, qa2, qa3); ISS(qa0, qa1, qa2, qa3, baseZ + 2048);        // g0 -> g4
        CONS(aZ[1], af, qb0, qb1, qb2, qb3); ISS(qb0, qb1, qb2, qb3, baseZ + 4096 + 2048); // g1 -> g5
        #pragma unroll
        for (int t = 0; t < 2; ++t)
            #pragma unroll
            for (int kk = 0; kk < 4; ++kk)
                aR[t] = mfma16(af[kk], ldsRf(t, kk), aR[t]);
        CONS(aS[0], af, qc0, qc1, qc2, qc3); ISS(qc0, qc1, qc2, qc3, baseS + 2048);        // g2 -> g6
        CONS(aS[1], af, qd0, qd1, qd2, qd3); ISS(qd0, qd1, qd2, qd3, baseS + 4096 + 2048); // g3 -> g7
        ldAF(af, bE, 1);                                             // h1
        CONS(aZ[0], af, qa0, qa1, qa2, qa3); ISS(qa0, qa1, qa2, qa3, baseC);           // g4 -> g8
        CONS(aZ[1], af, qb0, qb1, qb2, qb3); ISS(qb0, qb1, qb2, qb3, baseC + 4096);    // g5 -> g9
        #pragma unroll
        for (int t = 0; t < 2; ++t)
            #pragma unroll
            for (int kk = 0; kk < 4; ++kk)
                aR[t] = mfma16(af[kk], ldsRf(t, 4 + kk), aR[t]);
        CONS(aS[0], af, qc0, qc1, qc2, qc3); ISS(qc0, qc1, qc2, qc3, baseC + 2048);        // g6 -> g10
        CONS(aS[1], af, qd0, qd1, qd2, qd3); ISS(qd0, qd1, qd2, qd3, baseC + 4096 + 2048); // g7 -> g11

        // epilogue-1: z,r in regs; write r*E and tanh(S1) tiles
        #pragma unroll
        for (int t = 0; t < 2; ++t)
            #pragma unroll
            for (int r = 0; r < 4; ++r) {
                zreg[t][r] = sigm(aZ[t][r] + bz[t]);
                float rr   = sigm(aR[t][r] + br[t]);
                float s    = ftanh(aS[t][r] + bs1[t]);
                int row = 4 * lg + r, col = 32 * wv + 16 * t + lr;
                st16(bTS, row, col, f2bf(s));
                st16(bRE, row, col, f2bf(rr * Ev[t][r]));
            }
        barrier_lgkm();   // B2

        // ---- P2a: C = (r*E)@Wc^T ;  P2b: T1 = tanh(S1)@Wz^T ----
        f32x4 aC[2], aT[2];
        #pragma unroll
        for (int t = 0; t < 2; ++t) {
            aC[t] = f32x4{0.f, 0.f, 0.f, 0.f};
            aT[t] = f32x4{0.f, 0.f, 0.f, 0.f};
        }
        ldAF(af, bRE, 0);
        CONS(aC[0], af, qa0, qa1, qa2, qa3); ISS(qa0, qa1, qa2, qa3, baseT);           // g8  -> g12
        CONS(aC[1], af, qb0, qb1, qb2, qb3); ISS(qb0, qb1, qb2, qb3, baseT + 4096);    // g9  -> g13
        ldAF(af, bRE, 1);
        CONS(aC[0], af, qc0, qc1, qc2, qc3); ISS(qc0, qc1, qc2, qc3, baseT + 2048);        // g10 -> g14
        CONS(aC[1], af, qd0, qd1, qd2, qd3); ISS(qd0, qd1, qd2, qd3, baseT + 4096 + 2048); // g11 -> g15
        ldAF(af, bTS, 0);
        CONS(aT[0], af, qa0, qa1, qa2, qa3); ISS(qa0, qa1, qa2, qa3, baseF);           // g12 -> g16
        CONS(aT[1], af, qb0, qb1, qb2, qb3); ISS(qb0, qb1, qb2, qb3, baseF + 4096);    // g13 -> g17
        ldAF(af, bTS, 1);
        CONS(aT[0], af, qc0, qc1, qc2, qc3); ISS(qc0, qc1, qc2, qc3, baseF + 2048);        // g14 -> g18
        CONS(aT[1], af, qd0, qd1, qd2, qd3); ISS(qd0, qd1, qd2, qd3, baseF + 4096 + 2048); // g15 -> g19

        // epilogue-2: dh_temp -> X_E slot
        {
            float tm[2];
            #pragma unroll
            for (int t = 0; t < 2; ++t) tm[t] = ftanh(te * wtv[t]);
            #pragma unroll
            for (int t = 0; t < 2; ++t)
                #pragma unroll
                for (int r = 0; r < 4; ++r) {
                    float ht = ftanh(aC[t][r] + bc[t]) + tm[t];
                    float dh = (1.0f - zreg[t][r]) * (ht - Ev[t][r]);
                    st16(bE, 4 * lg + r, 32 * wv + 16 * t + lr, f2bf(dh));
                }
        }
        barrier_lgkm();   // B3

        // ---- P3: F = dh_temp@Wf1^T ----
        f32x4 aF[2];
        #pragma unroll
        for (int t = 0; t < 2; ++t) aF[t] = f32x4{0.f, 0.f, 0.f, 0.f};
        ldAF(af, bE, 0);
        CONS(aF[0], af, qa0, qa1, qa2, qa3); ISS(qa0, qa1, qa2, qa3, baseZ);           // g16 -> next g0
        CONS(aF[1], af, qb0, qb1, qb2, qb3); ISS(qb0, qb1, qb2, qb3, baseZ + 4096);    // g17 -> next g1
        ldAF(af, bE, 1);
        CONS(aF[0], af, qc0, qc1, qc2, qc3); ISS(qc0, qc1, qc2, qc3, baseS);           // g18 -> next g2
        CONS(aF[1], af, qd0, qd1, qd2, qd3); ISS(qd0, qd1, qd2, qd3, baseS + 4096);    // g19 -> next g3

        // epilogue-3: kv + RK fold (rounding order identical to reference)
        if (RK == 1) {
            #pragma unroll
            for (int t = 0; t < 2; ++t)
                #pragma unroll
                for (int r = 0; r < 4; ++r)
                    kA[t][r] = ftanh(aF[t][r] + aT[t][r] + bfv[t]);
        } else if (RK == 2) {
            #pragma unroll
            for (int t = 0; t < 2; ++t)
                #pragma unroll
                for (int r = 0; r < 4; ++r)
                    kB[t][r] = ftanh(aF[t][r] + aT[t][r] + bfv[t]);
        } else if (RK == 3) {
            #pragma unroll
            for (int t = 0; t < 2; ++t)
                #pragma unroll
                for (int r = 0; r < 4; ++r) {
                    float v = ftanh(aF[t][r] + aT[t][r] + bfv[t]);
                    float a = kA[t][r], b = kB[t][r];
                    kA[t][r] = a + 3.0f * (b + v);   // k1 + 3*(k2+k3)
                    kB[t][r] = (a - b) + v;          // (k1-k2)+k3
                }
        } else {
            #pragma unroll
            for (int t = 0; t < 2; ++t)
                #pragma unroll
                for (int r = 0; r < 4; ++r) {
                    float v = ftanh(aF[t][r] + aT[t][r] + bfv[t]);
                    y[t][r] += dt * 0.125f * (kA[t][r] + v);
                }
        }

        // rotate activation slots (WAR-safe across B1)
        int tmp = bE; bE = bRE; bRE = bTS; bTS = tmp;
    };

    for (int b = 0; b < BATCH; ++b) {
        float t0 = tspans[2 * b], t1 = tspans[2 * b + 1];
        dt = (t1 - t0) / 10.0f;
        for (int s = 0; s < NSTEPS; ++s) {
            float tb = t0 + (float)s * dt;
            EVAL(tb, 1);
            EVAL(tb + dt * third, 2);
            EVAL(tb + dt * 2.0f * third, 3);
            EVAL(tb + dt, 4);
        }
        #pragma unroll
        for (int t = 0; t < 2; ++t)
            #pragma unroll
            for (int r = 0; r < 4; ++r) {
                int row = wg * MTILE + 4 * lg + r;
                out[(b * NROWS + row) * 256 + (32 * wv + 16 * t + lr)] = y[t][r];
            }
    }
}

extern "C" void kernel_launch(void* const* d_in, const int* in_sizes, int n_in,
                              void* d_out, int out_size, void* d_ws, size_t ws_size,
                              hipStream_t stream) {
    (void)in_sizes; (void)n_in; (void)out_size; (void)ws_size;
    const float* h0    = (const float*)d_in[0];
    const float* ts    = (const float*)d_in[1];
    // d_in[2] = adj_matrices : unused (spectral_reg is None)
    const float* Wg_w  = (const float*)d_in[3];
    const float* Wg_b  = (const float*)d_in[4];
    const float* Wc_w  = (const float*)d_in[5];
    const float* Wc_b  = (const float*)d_in[6];
    const float* Wt_w  = (const float*)d_in[7];
    const float* Ws1_w = (const float*)d_in[8];
    const float* Ws1_b = (const float*)d_in[9];
    const float* Ws2_w = (const float*)d_in[10];
    const float* Ws2_b = (const float*)d_in[11];
    const float* Wf_w  = (const float*)d_in[12];
    const float* Wf_b  = (const float*)d_in[13];

    char* ws = (char*)d_ws;
    u16*   P1    = (u16*)(ws);              // 393216 B
    u16*   P2    = (u16*)(ws + 393216);     // 262144 B
    u16*   P3    = (u16*)(ws + 655360);     // 131072 B
    float* Wz    = (float*)(ws + 786432);   // 262144 B
    float* biasf = (float*)(ws + 1048576);  //   1024 B

    hipLaunchKernelGGL(stode_wz,    dim3(256),  dim3(256), 0, stream, Wf_w, Ws2_w, Wz);
    hipLaunchKernelGGL(stode_biasf, dim3(1),    dim3(256), 0, stream, Wf_w, Ws2_b, Wf_b, biasf);
    hipLaunchKernelGGL(stode_pack,  dim3(1536), dim3(256), 0, stream, Wg_w, Ws1_w, Wc_w, Wz, Wf_w, P1, P2, P3);
    hipLaunchKernelGGL(stode_main,  dim3(NWGS), dim3(THREADS), 0, stream,
                       h0, ts, Wg_b, Wc_b, Wt_w, Ws1_b, P1, P2, P3, biasf, (float*)d_out);
}

// Round 12
// 1893.136 us; speedup vs baseline: 1.2600x; 1.2600x over previous
//
#include <hip/hip_runtime.h>
#include <stdint.h>

typedef unsigned short u16;
typedef unsigned int   u32;

typedef short bf16x8 __attribute__((ext_vector_type(8)));   // 8 bf16 in 4 VGPRs
typedef int   i32x4  __attribute__((ext_vector_type(4)));
typedef float f32x4  __attribute__((ext_vector_type(4)));

#define NROWS  2048
#define HID    256
#define BATCH  8
#define NSTEPS 10
#define MTILE  16            // rows per workgroup
#define NWGS   (NROWS/MTILE) // 128
#define THREADS 512          // 8 waves, 2/SIMD, 128-VGPR budget (R9-proven)

// ---------- helpers ----------
__device__ __forceinline__ u16 f2bf(float f) {
    union { float f; u32 u; } v; v.f = f;
    u32 r = (v.u + 0x7FFFu + ((v.u >> 16) & 1u)) >> 16;   // RNE
    return (u16)r;
}
// fast sigmoid/tanh: v_rcp_f32 instead of IEEE divide (10 inst -> 2).
// ~1-ulp fp32 perturbation, negligible vs the bf16 noise floor of this pipeline.
__device__ __forceinline__ float sigm(float x) {
    return __builtin_amdgcn_rcpf(1.0f + __expf(-x));
}
__device__ __forceinline__ float ftanh(float x) {
    x = fminf(fmaxf(x, -15.0f), 15.0f);
    float a = __expf(2.0f * x);
    return (a - 1.0f) * __builtin_amdgcn_rcpf(a + 1.0f);
}
__device__ __forceinline__ f32x4 mfma16(bf16x8 a, bf16x8 b, f32x4 c) {
    return __builtin_amdgcn_mfma_f32_16x16x32_bf16(a, b, c, 0, 0, 0);
}
__device__ __forceinline__ bf16x8 as_bf(i32x4 v) {
    union { i32x4 i; bf16x8 b; } u; u.i = v; return u.b;
}
// packed weight B-fragment load (plain path, residency fill only)
__device__ __forceinline__ bf16x8 loadB(const u16* __restrict__ base, int ct, int kt, int ln) {
    return ((const bf16x8*)base)[(ct * 8 + kt) * 64 + ln];
}
// barrier that does NOT drain vmcnt (stream loads stay in flight)
__device__ __forceinline__ void barrier_lgkm() {
    asm volatile("s_waitcnt lgkmcnt(0)" ::: "memory");
    __builtin_amdgcn_s_barrier();
    asm volatile("" ::: "memory");
}

// asm-pinned 4-frag (4KB) weight-group load; nt = non-temporal (read-once
// stream, don't displace L1 lines the A-tile/bias path wants).
#define ISS(q0, q1, q2, q3, P) do {                                              \
    uint64_t _a = (uint64_t)(const void*)(P);                                    \
    asm volatile("global_load_dwordx4 %0, %1, off nt"             : "=v"(q0) : "v"(_a)); \
    asm volatile("global_load_dwordx4 %0, %1, off offset:1024 nt" : "=v"(q1) : "v"(_a)); \
    asm volatile("global_load_dwordx4 %0, %1, off offset:2048 nt" : "=v"(q2) : "v"(_a)); \
    asm volatile("global_load_dwordx4 %0, %1, off offset:3072 nt" : "=v"(q3) : "v"(_a)); \
} while (0)

// consume a group: counted wait (1 younger group = 4 loads stays in flight);
// sched_barrier(0) = FULL fence (rule #18; R10's relaxed mask corrupted data).
#define CONS(acc, AF, q0, q1, q2, q3) do {                                       \
    asm volatile("s_waitcnt vmcnt(4)" ::: "memory");                             \
    __builtin_amdgcn_sched_barrier(0);                                           \
    (acc) = mfma16(AF[0], as_bf(q0), (acc));                                     \
    (acc) = mfma16(AF[1], as_bf(q1), (acc));                                     \
    (acc) = mfma16(AF[2], as_bf(q2), (acc));                                     \
    (acc) = mfma16(AF[3], as_bf(q3), (acc));                                     \
} while (0)

// ---------- setup kernels (unchanged, validated) ----------
__global__ __launch_bounds__(256) void stode_wz(const float* __restrict__ Wf,
                                                const float* __restrict__ Ws2,
                                                float* __restrict__ Wz) {
    int a = blockIdx.x;
    int b = threadIdx.x;
    const float* wf2 = Wf + a * 512 + 256;
    float acc = 0.0f;
    for (int c = 0; c < 256; ++c) acc += wf2[c] * Ws2[c * 256 + b];
    Wz[a * 256 + b] = acc;
}
__global__ __launch_bounds__(256) void stode_biasf(const float* __restrict__ Wf,
                                                   const float* __restrict__ Ws2b,
                                                   const float* __restrict__ Wfb,
                                                   float* __restrict__ biasf) {
    int a = threadIdx.x;
    const float* wf2 = Wf + a * 512 + 256;
    float acc = Wfb[a];
    for (int c = 0; c < 256; ++c) acc += wf2[c] * Ws2b[c];
    biasf[a] = acc;
}
__global__ __launch_bounds__(256) void stode_pack(const float* __restrict__ Wg,
                                                  const float* __restrict__ Ws1,
                                                  const float* __restrict__ Wc,
                                                  const float* __restrict__ Wz,
                                                  const float* __restrict__ Wf,
                                                  u16* __restrict__ P1,
                                                  u16* __restrict__ P2,
                                                  u16* __restrict__ P3) {
    int i = blockIdx.x * 256 + threadIdx.x;
    const int NP1 = 48 * 8 * 64 * 8;
    const int NP2 = 32 * 8 * 64 * 8;
    int region, local;
    if (i < NP1)            { region = 0; local = i; }
    else if (i < NP1 + NP2) { region = 1; local = i - NP1; }
    else                    { region = 2; local = i - NP1 - NP2; }
    int j    = local & 7;
    int lane = (local >> 3) & 63;
    int kt   = (local >> 9) & 7;
    int ct   = local >> 12;
    int k = kt * 32 + (lane >> 4) * 8 + j;
    int c = lane & 15;
    if (region == 0) {
        float v = (ct < 32) ? Wg[(16 * ct + c) * 256 + k]
                            : Ws1[(16 * (ct - 32) + c) * 256 + k];
        P1[local] = f2bf(v);
    } else if (region == 1) {
        float v = (ct < 16) ? Wc[(16 * ct + c) * 256 + k]
                            : Wz[(16 * (ct - 16) + c) * 256 + k];
        P2[local] = f2bf(v);
    } else {
        float v = Wf[(16 * ct + c) * 512 + k];
        P3[local] = f2bf(v);
    }
}

// ---------- main persistent integrator ----------
// LDS: 3 rotating 8KB activation slots @0/8192/16384; R-resident @24576 (128KB). 152KB.
#define SLOT0 0
#define SLOT1 8192
#define SLOT2 16384
#define WLB   24576

__global__ __launch_bounds__(THREADS, 2) void stode_main(
    const float* __restrict__ h0, const float* __restrict__ tspans,
    const float* __restrict__ Wg_b, const float* __restrict__ Wc_b,
    const float* __restrict__ Wt,   const float* __restrict__ Ws1_b,
    const u16* __restrict__ P1p, const u16* __restrict__ P2p, const u16* __restrict__ P3p,
    const float* __restrict__ biasf, float* __restrict__ out)
{
    __shared__ __align__(1024) u16 SH[77824];   // 155648 bytes
    char* shb = (char*)SH;

    const int tid = threadIdx.x;
    const int wv  = tid >> 6;    // 0..7 : wave owns cts {2wv, 2wv+1} (cols 32wv..32wv+31)
    const int ln  = tid & 63;
    const int lr  = ln & 15;
    const int lg  = ln >> 4;
    const int wg  = blockIdx.x;
    const float third = 1.0f / 3.0f;

    // A-frag read bases: addr(k) = (k even ? tbE : tbO) + xb + k*64 (XOR swizzle)
    const int base0 = lr * 512 + ((lg * 16) ^ ((lr & 3) << 4));
    const int flp   = (lr & 4) ? 64 : 0;
    const int tbE   = base0 + flp;
    const int tbO   = base0 - flp;
    const int rBase = WLB + (wv << 14) + (ln << 4);   // R-resident: 16KB/wave

    auto ldAF = [&](bf16x8 (&af)[4], int xb, int ktH) {
        #pragma unroll
        for (int kk = 0; kk < 4; ++kk) {
            int k = 4 * ktH + kk;
            af[kk] = *(const bf16x8*)(shb + ((k & 1) ? tbO : tbE) + xb + k * 64);
        }
    };
    auto st16 = [&](int xb, int row, int col, u16 v) {
        int byte = (xb + row * 512 + col * 2) ^ ((row & 7) << 4);
        *(u16*)(shb + byte) = v;
    };
    auto ldsRf = [&](int t, int kt) -> bf16x8 {
        return *(const bf16x8*)(shb + rBase + ((t * 8 + kt) << 10));
    };

    // ---- one-time residency: R weights -> LDS (16 frags/wave) ----
    #pragma unroll
    for (int t = 0; t < 2; ++t)
        #pragma unroll
        for (int kt = 0; kt < 8; ++kt) {
            bf16x8 f = loadB(P1p, 16 + 2 * wv + t, kt, ln);
            *(bf16x8*)(shb + rBase + ((t * 8 + kt) << 10)) = f;
        }

    // stream base pointers (u16 units; frag = 512 u16, ct-block = 4096 u16, half = 2048)
    const u16* const baseZ = P1p + (2 * wv) * 4096 + ln * 8;
    const u16* const baseS = P1p + (32 + 2 * wv) * 4096 + ln * 8;
    const u16* const baseC = P2p + (2 * wv) * 4096 + ln * 8;
    const u16* const baseT = P2p + (16 + 2 * wv) * 4096 + ln * 8;
    const u16* const baseF = P3p + (2 * wv) * 4096 + ln * 8;

    // biases / Wt : cols = 32wv+lr, 32wv+16+lr
    float bz[2], br[2], bs1[2], bc[2], bfv[2], wtv[2];
    #pragma unroll
    for (int t = 0; t < 2; ++t) {
        int c = 32 * wv + 16 * t + lr;
        bz[t]  = Wg_b[c];
        br[t]  = Wg_b[256 + c];
        bs1[t] = Ws1_b[c];
        bc[t]  = Wc_b[c];
        bfv[t] = biasf[c];
        wtv[t] = Wt[c];
    }

    // state at C/D positions: row = 4*lg + r, col = 32wv + 16t + lr
    float y[2][4], kA[2][4], kB[2][4], zreg[2][4];
    #pragma unroll
    for (int t = 0; t < 2; ++t)
        #pragma unroll
        for (int r = 0; r < 4; ++r)
            y[t][r] = h0[(wg * MTILE + 4 * lg + r) * 256 + (32 * wv + 16 * t + lr)];

    __syncthreads();   // residency visible (full drain, once)

    // stream buffers (asm-pinned, 2 x 16 regs)
    i32x4 qa0, qa1, qa2, qa3, qb0, qb1, qb2, qb3;
    // prologue: g0 = Z t0 h0 -> A, g1 = Z t1 h0 -> B
    ISS(qa0, qa1, qa2, qa3, baseZ);
    ISS(qb0, qb1, qb2, qb3, baseZ + 4096);

    float dt = 0.0f;

    auto calcE = [&](float (&Ev)[2][4], int RK) {
        if (RK == 1) {
            #pragma unroll
            for (int t = 0; t < 2; ++t)
                #pragma unroll
                for (int r = 0; r < 4; ++r) Ev[t][r] = y[t][r];
        } else if (RK == 2) {
            float c = dt * third;
            #pragma unroll
            for (int t = 0; t < 2; ++t)
                #pragma unroll
                for (int r = 0; r < 4; ++r) Ev[t][r] = y[t][r] + c * kA[t][r];
        } else if (RK == 3) {
            #pragma unroll
            for (int t = 0; t < 2; ++t)
                #pragma unroll
                for (int r = 0; r < 4; ++r) Ev[t][r] = y[t][r] + dt * (kB[t][r] - third * kA[t][r]);
        } else {
            #pragma unroll
            for (int t = 0; t < 2; ++t)
                #pragma unroll
                for (int r = 0; r < 4; ++r) Ev[t][r] = y[t][r] + dt * kB[t][r];
        }
    };

    // rotating activation slots
    int bE = SLOT0, bRE = SLOT1, bTS = SLOT2;

    auto EVAL = [&](float te, int RK) {
        // E computed ONCE per eval (bit-identical expressions), reused 3x
        float Ev[2][4]; calcE(Ev, RK);

        // stage X_E = bf16(E)
        #pragma unroll
        for (int t = 0; t < 2; ++t)
            #pragma unroll
            for (int r = 0; r < 4; ++r)
                st16(bE, 4 * lg + r, 32 * wv + 16 * t + lr, f2bf(Ev[t][r]));
        barrier_lgkm();   // B1 (stream loads stay in flight)

        // ---- P1: Z (stream), R (LDS-resident), S (stream) ----
        f32x4 aZ[2], aR[2], aS[2];
        #pragma unroll
        for (int t = 0; t < 2; ++t) {
            aZ[t] = f32x4{0.f, 0.f, 0.f, 0.f};
            aR[t] = f32x4{0.f, 0.f, 0.f, 0.f};
            aS[t] = f32x4{0.f, 0.f, 0.f, 0.f};
        }
        bf16x8 af[4];
        ldAF(af, bE, 0);                                             // h0
        CONS(aZ[0], af, qa0, qa1, qa2, qa3); ISS(qa0, qa1, qa2, qa3, baseS);           // g0 -> g2
        CONS(aZ[1], af, qb0, qb1, qb2, qb3); ISS(qb0, qb1, qb2, qb3, baseS + 4096);    // g1 -> g3
        #pragma unroll
        for (int t = 0; t < 2; ++t)
            #pragma unroll
            for (int kk = 0; kk < 4; ++kk)
                aR[t] = mfma16(af[kk], ldsRf(t, kk), aR[t]);
        CONS(aS[0], af, qa0, qa1, qa2, qa3); ISS(qa0, qa1, qa2, qa3, baseZ + 2048);        // g2 -> g4
        CONS(aS[1], af, qb0, qb1, qb2, qb3); ISS(qb0, qb1, qb2, qb3, baseZ + 4096 + 2048); // g3 -> g5
        ldAF(af, bE, 1);                                             // h1
        CONS(aZ[0], af, qa0, qa1, qa2, qa3); ISS(qa0, qa1, qa2, qa3, baseS + 2048);        // g4 -> g6
        CONS(aZ[1], af, qb0, qb1, qb2, qb3); ISS(qb0, qb1, qb2, qb3, baseS + 4096 + 2048); // g5 -> g7
        #pragma unroll
        for (int t = 0; t < 2; ++t)
            #pragma unroll
            for (int kk = 0; kk < 4; ++kk)
                aR[t] = mfma16(af[kk], ldsRf(t, 4 + kk), aR[t]);
        CONS(aS[0], af, qa0, qa1, qa2, qa3); ISS(qa0, qa1, qa2, qa3, baseC);           // g6 -> g8
        CONS(aS[1], af, qb0, qb1, qb2, qb3); ISS(qb0, qb1, qb2, qb3, baseC + 4096);    // g7 -> g9

        // epilogue-1: z,r in regs; write r*E and tanh(S1) tiles
        #pragma unroll
        for (int t = 0; t < 2; ++t)
            #pragma unroll
            for (int r = 0; r < 4; ++r) {
                zreg[t][r] = sigm(aZ[t][r] + bz[t]);
                float rr   = sigm(aR[t][r] + br[t]);
                float s    = ftanh(aS[t][r] + bs1[t]);
                int row = 4 * lg + r, col = 32 * wv + 16 * t + lr;
                st16(bTS, row, col, f2bf(s));
                st16(bRE, row, col, f2bf(rr * Ev[t][r]));
            }
        barrier_lgkm();   // B2

        // ---- P2a: C = (r*E)@Wc^T ;  P2b: T1 = tanh(S1)@Wz^T ----
        f32x4 aC[2], aT[2];
        #pragma unroll
        for (int t = 0; t < 2; ++t) {
            aC[t] = f32x4{0.f, 0.f, 0.f, 0.f};
            aT[t] = f32x4{0.f, 0.f, 0.f, 0.f};
        }
        ldAF(af, bRE, 0);
        CONS(aC[0], af, qa0, qa1, qa2, qa3); ISS(qa0, qa1, qa2, qa3, baseC + 2048);        // g8  -> g10
        CONS(aC[1], af, qb0, qb1, qb2, qb3); ISS(qb0, qb1, qb2, qb3, baseC + 4096 + 2048); // g9  -> g11
        ldAF(af, bRE, 1);
        CONS(aC[0], af, qa0, qa1, qa2, qa3); ISS(qa0, qa1, qa2, qa3, baseT);           // g10 -> g12
        CONS(aC[1], af, qb0, qb1, qb2, qb3); ISS(qb0, qb1, qb2, qb3, baseT + 4096);    // g11 -> g13
        ldAF(af, bTS, 0);
        CONS(aT[0], af, qa0, qa1, qa2, qa3); ISS(qa0, qa1, qa2, qa3, baseT + 2048);        // g12 -> g14
        CONS(aT[1], af, qb0, qb1, qb2, qb3); ISS(qb0, qb1, qb2, qb3, baseT + 4096 + 2048); // g13 -> g15
        ldAF(af, bTS, 1);
        CONS(aT[0], af, qa0, qa1, qa2, qa3); ISS(qa0, qa1, qa2, qa3, baseF);           // g14 -> g16
        CONS(aT[1], af, qb0, qb1, qb2, qb3); ISS(qb0, qb1, qb2, qb3, baseF + 4096);    // g15 -> g17

        // epilogue-2: dh_temp -> X_E slot
        {
            float tm[2];
            #pragma unroll
            for (int t = 0; t < 2; ++t) tm[t] = ftanh(te * wtv[t]);
            #pragma unroll
            for (int t = 0; t < 2; ++t)
                #pragma unroll
                for (int r = 0; r < 4; ++r) {
                    float ht = ftanh(aC[t][r] + bc[t]) + tm[t];
                    float dh = (1.0f - zreg[t][r]) * (ht - Ev[t][r]);
                    st16(bE, 4 * lg + r, 32 * wv + 16 * t + lr, f2bf(dh));
                }
        }
        barrier_lgkm();   // B3

        // ---- P3: F = dh_temp@Wf1^T ----
        f32x4 aF[2];
        #pragma unroll
        for (int t = 0; t < 2; ++t) aF[t] = f32x4{0.f, 0.f, 0.f, 0.f};
        ldAF(af, bE, 0);
        CONS(aF[0], af, qa0, qa1, qa2, qa3); ISS(qa0, qa1, qa2, qa3, baseF + 2048);        // g16 -> g18
        CONS(aF[1], af, qb0, qb1, qb2, qb3); ISS(qb0, qb1, qb2, qb3, baseF + 4096 + 2048); // g17 -> g19
        ldAF(af, bE, 1);
        CONS(aF[0], af, qa0, qa1, qa2, qa3); ISS(qa0, qa1, qa2, qa3, baseZ);           // g18 -> next g0
        CONS(aF[1], af, qb0, qb1, qb2, qb3); ISS(qb0, qb1, qb2, qb3, baseZ + 4096);    // g19 -> next g1

        // epilogue-3: kv + RK fold (rounding order identical to reference)
        if (RK == 1) {
            #pragma unroll
            for (int t = 0; t < 2; ++t)
                #pragma unroll
                for (int r = 0; r < 4; ++r)
                    kA[t][r] = ftanh(aF[t][r] + aT[t][r] + bfv[t]);
        } else if (RK == 2) {
            #pragma unroll
            for (int t = 0; t < 2; ++t)
                #pragma unroll
                for (int r = 0; r < 4; ++r)
                    kB[t][r] = ftanh(aF[t][r] + aT[t][r] + bfv[t]);
        } else if (RK == 3) {
            #pragma unroll
            for (int t = 0; t < 2; ++t)
                #pragma unroll
                for (int r = 0; r < 4; ++r) {
                    float v = ftanh(aF[t][r] + aT[t][r] + bfv[t]);
                    float a = kA[t][r], b = kB[t][r];
                    kA[t][r] = a + 3.0f * (b + v);   // k1 + 3*(k2+k3)
                    kB[t][r] = (a - b) + v;          // (k1-k2)+k3
                }
        } else {
            #pragma unroll
            for (int t = 0; t < 2; ++t)
                #pragma unroll
                for (int r = 0; r < 4; ++r) {
                    float v = ftanh(aF[t][r] + aT[t][r] + bfv[t]);
                    y[t][r] += dt * 0.125f * (kA[t][r] + v);
                }
        }

        // rotate activation slots (WAR-safe across B1)
        int tmp = bE; bE = bRE; bRE = bTS; bTS = tmp;
    };

    for (int b = 0; b < BATCH; ++b) {
        float t0 = tspans[2 * b], t1 = tspans[2 * b + 1];
        dt = (t1 - t0) / 10.0f;
        for (int s = 0; s < NSTEPS; ++s) {
            float tb = t0 + (float)s * dt;
            EVAL(tb, 1);
            EVAL(tb + dt * third, 2);
            EVAL(tb + dt * 2.0f * third, 3);
            EVAL(tb + dt, 4);
        }
        #pragma unroll
        for (int t = 0; t < 2; ++t)
            #pragma unroll
            for (int r = 0; r < 4; ++r) {
                int row = wg * MTILE + 4 * lg + r;
                out[(b * NROWS + row) * 256 + (32 * wv + 16 * t + lr)] = y[t][r];
            }
    }
}

extern "C" void kernel_launch(void* const* d_in, const int* in_sizes, int n_in,
                              void* d_out, int out_size, void* d_ws, size_t ws_size,
                              hipStream_t stream) {
    (void)in_sizes; (void)n_in; (void)out_size; (void)ws_size;
    const float* h0    = (const float*)d_in[0];
    const float* ts    = (const float*)d_in[1];
    // d_in[2] = adj_matrices : unused (spectral_reg is None)
    const float* Wg_w  = (const float*)d_in[3];
    const float* Wg_b  = (const float*)d_in[4];
    const float* Wc_w  = (const float*)d_in[5];
    const float* Wc_b  = (const float*)d_in[6];
    const float* Wt_w  = (const float*)d_in[7];
    const float* Ws1_w = (const float*)d_in[8];
    const float* Ws1_b = (const float*)d_in[9];
    const float* Ws2_w = (const float*)d_in[10];
    const float* Ws2_b = (const float*)d_in[11];
    const float* Wf_w  = (const float*)d_in[12];
    const float* Wf_b  = (const float*)d_in[13];

    char* ws = (char*)d_ws;
    u16*   P1    = (u16*)(ws);              // 393216 B
    u16*   P2    = (u16*)(ws + 393216);     // 262144 B
    u16*   P3    = (u16*)(ws + 655360);     // 131072 B
    float* Wz    = (float*)(ws + 786432);   // 262144 B
    float* biasf = (float*)(ws + 1048576);  //   1024 B

    hipLaunchKernelGGL(stode_wz,    dim3(256),  dim3(256), 0, stream, Wf_w, Ws2_w, Wz);
    hipLaunchKernelGGL(stode_biasf, dim3(1),    dim3(256), 0, stream, Wf_w, Ws2_b, Wf_b, biasf);
    hipLaunchKernelGGL(stode_pack,  dim3(1536), dim3(256), 0, stream, Wg_w, Ws1_w, Wc_w, Wz, Wf_w, P1, P2, P3);
    hipLaunchKernelGGL(stode_main,  dim3(NWGS), dim3(THREADS), 0, stream,
                       h0, ts, Wg_b, Wc_b, Wt_w, Ws1_b, P1, P2, P3, biasf, (float*)d_out);
}